// Round 2
// baseline (5759.101 us; speedup 1.0000x reference)
//
#include <hip/hip_runtime.h>
#include <math.h>

#define T_   32
#define N_   64
#define NL   64
#define E_   128
#define G3   384   // 3*E
#define NE   4
#define CH   64
#define D_   16
#define HW   16
#define RH   64
#define LE   64
#define HD   512
#define A_   16
#define INVN 32
#define KCOLS 9216 // CH*D_*3*3
#define OUTW 663

__device__ __forceinline__ float sigf(float x) { return 1.f/(1.f+expf(-x)); }

// ---------------- prep kernels ----------------

__global__ __launch_bounds__(128) void k_prep_M(const int* lines, const float* emb_task, float* M) {
    int nl = blockIdx.x;
    int i  = threadIdx.x;
    const int* ln = lines + nl*4;
    float s = 0.f;
    #pragma unroll
    for (int t = 0; t < 4; ++t) s += emb_task[ln[t]*E_ + i];
    M[nl*E_ + i] = s;
}

// T4[((dir*32 + k/4)*384 + g)*4 + (k%4)] = w[dir][g*128+k]
__global__ __launch_bounds__(128) void k_prep_T4(const float* wif, const float* wib,
                                                 const float* whf, const float* whb,
                                                 float* wiT4, float* whT4) {
    int g = blockIdx.x % 384, dir = blockIdx.x / 384;
    int k = threadIdx.x;
    const float* wi = dir ? wib : wif;
    const float* wh = dir ? whb : whf;
    int dst = ((dir*32 + (k>>2))*384 + g)*4 + (k&3);
    wiT4[dst] = wi[g*128 + k];
    whT4[dst] = wh[g*128 + k];
}

__global__ __launch_bounds__(128) void k_prep_misc(const int* p0, const float* M, int* p_cur, float* mp) {
    int n = blockIdx.x, i = threadIdx.x;
    int p = p0[n];
    if (i == 0) p_cur[n] = p;
    mp[n*E_ + i] = M[(n*NL + p)*E_ + i];
}

__global__ __launch_bounds__(64) void k_prep_invpa(const float* inv, const float* inv_w, const float* inv_b,
                                                   const int* pa, const float* emb_lower,
                                                   float* inv_all, float* pa_all) {
    int tn = blockIdx.x, r = threadIdx.x;
    const float* iv = inv + tn*INVN;
    float acc = inv_b[r];
    #pragma unroll
    for (int i = 0; i < INVN; ++i) acc += iv[i]*inv_w[i*RH + r];
    inv_all[tn*RH + r] = fmaxf(acc, 0.f);
    const int* pp = pa + tn*4;
    float s = 0.f;
    #pragma unroll
    for (int j = 0; j < 4; ++j) s += emb_lower[pp[j]*LE + r];
    pa_all[tn*LE + r] = s;
}

// giM[dir][n][l][g] = M[n][l] . wi[g] + bi[g]
__global__ __launch_bounds__(384) void k_giM(const float* M, const float* wiT4,
                                             const float* bif, const float* bib, float* giM) {
    int lblk = blockIdx.x, n = blockIdx.y, dir = blockIdx.z;
    int g = threadIdx.x;
    __shared__ float Ml[8][E_];
    for (int idx = g; idx < 8*E_; idx += 384) {
        int r = idx >> 7, k = idx & 127;
        Ml[r][k] = M[(n*NL + lblk*8 + r)*E_ + k];
    }
    __syncthreads();
    float acc[8];
    #pragma unroll
    for (int r = 0; r < 8; ++r) acc[r] = 0.f;
    const float4* W = (const float4*)(wiT4) + dir*32*384;
    for (int kq = 0; kq < 32; ++kq) {
        float4 w = W[kq*384 + g];
        #pragma unroll
        for (int r = 0; r < 8; ++r) {
            float4 h = *(const float4*)&Ml[r][kq*4];
            acc[r] += w.x*h.x + w.y*h.y + w.z*h.z + w.w*h.w;
        }
    }
    float bi = dir ? bib[g] : bif[g];
    #pragma unroll
    for (int r = 0; r < 8; ++r)
        giM[((dir*N_ + n)*NL + lblk*8 + r)*G3 + g] = acc[r] + bi;
}

// GRU over all rolls. grid (pblk 4, n 64, dir 2) = 512 wgs, 256 thr.
// 16 sequences per wg; thread: i = tid&127 (hidden idx), sb = tid>>7 (8 seqs each).
__global__ __launch_bounds__(256) void k_gru(const float* giM, const float* whT4,
                                             const float* bhf, const float* bhb,
                                             const float* beta_w, const float* beta_b,
                                             float* Ball) {
    int pblk = blockIdx.x, n = blockIdx.y, dir = blockIdx.z;
    int tid = threadIdx.x;
    int i = tid & 127;
    int sb = tid >> 7;

    __shared__ float Hs[16][132];
    __shared__ float bw[E_][NE];
    for (int idx = tid; idx < 16*132; idx += 256) ((float*)Hs)[idx] = 0.f;
    for (int idx = tid; idx < E_*NE; idx += 256) ((float*)bw)[idx] = beta_w[idx];
    const float* bh = dir ? bhb : bhf;
    float bhr = bh[i], bhz = bh[128+i], bhn = bh[256+i];
    const float4* W = (const float4*)(whT4) + dir*32*384;
    const float* giBase = giM + (dir*N_ + n)*NL*G3;
    // beta-head thread mapping (all 256 threads)
    int bs = tid >> 4;          // seq 0..15
    int bpart = (tid >> 2) & 3; // k-quarter
    int be = tid & 3;           // expert
    float bbias = beta_b[be];
    __syncthreads();

    for (int j = 0; j < NL; ++j) {
        float accr[8], accz[8], accn[8];
        #pragma unroll
        for (int s = 0; s < 8; ++s) { accr[s]=bhr; accz[s]=bhz; accn[s]=bhn; }
        #pragma unroll 2
        for (int kq = 0; kq < 32; ++kq) {
            float4 wr = W[kq*384 + i];
            float4 wz = W[kq*384 + 128 + i];
            float4 wn = W[kq*384 + 256 + i];
            #pragma unroll
            for (int s = 0; s < 8; ++s) {
                float4 h = *(const float4*)&Hs[sb*8 + s][kq*4];
                accr[s] += wr.x*h.x + wr.y*h.y + wr.z*h.z + wr.w*h.w;
                accz[s] += wz.x*h.x + wz.y*h.y + wz.z*h.z + wz.w*h.w;
                accn[s] += wn.x*h.x + wn.y*h.y + wn.z*h.z + wn.w*h.w;
            }
        }
        float hnew[8];
        #pragma unroll
        for (int s = 0; s < 8; ++s) {
            int ss = sb*8 + s;
            int p  = pblk*16 + ss;
            int l  = dir ? ((p + 63 - j) & 63) : ((p + j) & 63);
            const float* gi = giBase + l*G3;
            float r  = sigf(gi[i]       + accr[s]);
            float z  = sigf(gi[128+i]   + accz[s]);
            float nn = tanhf(gi[256+i]  + r*accn[s]);
            hnew[s] = (1.f - z)*nn + z*Hs[ss][i];
        }
        __syncthreads();
        #pragma unroll
        for (int s = 0; s < 8; ++s) Hs[sb*8 + s][i] = hnew[s];
        __syncthreads();
        // beta head: 16 seqs x 4 e x 4 k-parts across all 256 threads
        {
            float acc = 0.f;
            const float* hrow = &Hs[bs][bpart*32];
            #pragma unroll 8
            for (int k = 0; k < 32; ++k) acc += hrow[k]*bw[bpart*32 + k][be];
            acc += __shfl_xor(acc, 4);
            acc += __shfl_xor(acc, 8);
            if (bpart == 0) {
                float bval = sigf(acc + bbias);
                int p = pblk*16 + bs;
                int j2 = 2*j + dir;
                Ball[((n*NL + p)*128 + j2)*NE + be] = bval;
            }
        }
    }
}

// stick-breaking -> reordered P_final[n][p][j][e]
__global__ __launch_bounds__(64) void k_P(const float* Ball, float* Pall) {
    int np = blockIdx.x;
    int tid = threadIdx.x;
    __shared__ float B[128][NE];
    __shared__ float Pf[128][NE];
    const float* src = Ball + np*128*NE;
    for (int idx = tid; idx < 128*NE; idx += 64) ((float*)B)[idx] = src[idx];
    __syncthreads();
    if (tid < NE) {
        int e = tid;
        float c = 1.f;
        for (int j2 = 0; j2 < 128; ++j2) {
            float bz = (j2 == 0 || j2 == 127) ? 0.f : B[j2][e];
            float bf = (j2 == 127) ? 1.f : bz;
            Pf[j2][e] = bf * c;
            c *= (1.f - bz);
        }
    }
    __syncthreads();
    float* dst = Pall + np*128*NE;
    for (int idx = tid; idx < 128*NE; idx += 64) {
        int j = idx >> 2, e = idx & 3;
        int jf = (j < 64) ? (2*(63 - j) + 1) : (2*(j - 64));
        dst[idx] = Pf[jf][e];
    }
}

// per-step GEMM: kern_buf[n][col] = mp[n] . kernel_w[:,col] + kernel_b[col]
__global__ __launch_bounds__(256) void k_kern(const float* mp, const float* kernel_w,
                                              const float* kernel_b, float* kern_buf) {
    int tid = threadIdx.x;
    int col = blockIdx.x*32 + (tid & 31);
    int rg  = tid >> 5;
    __shared__ float ml[E_][68];
    for (int idx = tid; idx < N_*E_; idx += 256) {
        int nn2 = idx >> 7, e = idx & 127;
        ml[e][nn2] = mp[idx];
    }
    __syncthreads();
    float acc[8];
    #pragma unroll
    for (int r = 0; r < 8; ++r) acc[r] = 0.f;
    for (int e = 0; e < E_; ++e) {
        float w = kernel_w[e*KCOLS + col];
        #pragma unroll
        for (int r = 0; r < 8; ++r) acc[r] += ml[e][rg*8 + r]*w;
    }
    float kb = kernel_b[col];
    #pragma unroll
    for (int r = 0; r < 8; ++r)
        kern_buf[(rg*8 + r)*KCOLS + col] = acc[r] + kb;
}

// fused per-step conv + heads: grid 64 (n), 512 thr
__global__ __launch_bounds__(512) void k_step(
    const float* obs, const float* kern_buf, const float* conv_bias,
    const float* mp_buf, const float* inv_all, const float* pa_all,
    const float* amask, const float* Pall, const float* M,
    const float* zw, const float* zb, const float* aw, const float* ab,
    const float* uw, const float* ub, const float* dw, const float* db,
    const float* cw, const float* cb,
    int* p_cur, float* out, int t) {
    int n = blockIdx.x, tid = threadIdx.x;
    __shared__ float ol[D_][HW][HW];      // 16 KB
    __shared__ float kl[KCOLS];           // 36 KB
    __shared__ float h1s[CH];
    __shared__ float zin[320];
    __shared__ float z1[HD];
    __shared__ float pla[A_][8];
    __shared__ float pc[32];
    __shared__ float plu[NE][32];
    __shared__ float pld[2][32];
    __shared__ float la[A_];
    __shared__ float lu[NE];
    __shared__ float ld2[2];
    __shared__ float uvals[NE];
    __shared__ float dp[128];
    __shared__ float sc[1];
    __shared__ int   si[4];   // 0: p, 2: dg, 3: p_new

    // stage loads
    const float4* op4 = (const float4*)(obs + (size_t)(t*N_ + n)*D_*HW*HW);
    float4* ol4 = (float4*)ol;
    #pragma unroll
    for (int r = 0; r < 2; ++r) ol4[tid + r*512] = op4[tid + r*512];
    const float4* kp4 = (const float4*)(kern_buf + (size_t)n*KCOLS);
    float4* kl4 = (float4*)kl;
    for (int idx = tid; idx < KCOLS/4; idx += 512) kl4[idx] = kp4[idx];
    if (tid == 0) si[0] = p_cur[n];
    __syncthreads();

    // conv: c = tid>>3, two rows per thread
    {
        int c = tid >> 3, sub = tid & 7;
        const float* kc = kl + c*144;
        float bc = conv_bias[c];
        float psum = 0.f;
        #pragma unroll
        for (int ry = 0; ry < 2; ++ry) {
            int y = sub*2 + ry;
            float acc[16];
            #pragma unroll
            for (int x = 0; x < 16; ++x) acc[x] = 0.f;
            for (int d = 0; d < D_; ++d) {
                const float* kd = kc + d*9;
                #pragma unroll
                for (int ky = 0; ky < 3; ++ky) {
                    int yy = y + ky - 1;
                    if (yy < 0 || yy >= HW) continue;
                    float row[18];
                    row[0] = 0.f; row[17] = 0.f;
                    const float4* rsrc = (const float4*)&ol[d][yy][0];
                    float4 r0 = rsrc[0], r1 = rsrc[1], r2 = rsrc[2], r3 = rsrc[3];
                    row[1]=r0.x; row[2]=r0.y; row[3]=r0.z; row[4]=r0.w;
                    row[5]=r1.x; row[6]=r1.y; row[7]=r1.z; row[8]=r1.w;
                    row[9]=r2.x; row[10]=r2.y; row[11]=r2.z; row[12]=r2.w;
                    row[13]=r3.x; row[14]=r3.y; row[15]=r3.z; row[16]=r3.w;
                    float k0 = kd[ky*3], k1 = kd[ky*3+1], k2 = kd[ky*3+2];
                    #pragma unroll
                    for (int x = 0; x < 16; ++x)
                        acc[x] += row[x]*k0 + row[x+1]*k1 + row[x+2]*k2;
                }
            }
            #pragma unroll
            for (int x = 0; x < 16; ++x) psum += fmaxf(acc[x] + bc, 0.f);
        }
        psum += __shfl_xor(psum, 1);
        psum += __shfl_xor(psum, 2);
        psum += __shfl_xor(psum, 4);
        if (sub == 0) h1s[c] = psum;
    }
    __syncthreads();

    // build zin
    if (tid < E_)            zin[tid] = mp_buf[n*E_ + tid];
    else if (tid < 192)      zin[tid] = h1s[tid - E_];
    else if (tid < 256)      zin[tid] = inv_all[(t*N_ + n)*RH + (tid - 192)];
    else if (tid < 320)      zin[tid] = pa_all[(t*N_ + n)*LE + (tid - 256)];
    __syncthreads();

    size_t ob = ((size_t)t*N_ + n)*OUTW;
    // z1: one h per thread
    {
        float acc = zb[tid];
        #pragma unroll 4
        for (int i2 = 0; i2 < 320; ++i2) acc += zin[i2]*zw[i2*HD + tid];
        float v = fmaxf(acc, 0.f);
        z1[tid] = v;
        out[ob + 146 + tid] = v;
    }
    __syncthreads();

    // stage A: partial sums for heads
    if (tid < 128) {                       // actor: 16 a x 8 parts x 64 MAC
        int a2 = tid >> 3, part = tid & 7;
        float acc = 0.f;
        const float* z0 = z1 + part*64;
        #pragma unroll 8
        for (int h = 0; h < 64; ++h) acc += z0[h]*aw[(part*64 + h)*A_ + a2];
        pla[a2][part] = acc;
    } else if (tid < 160) {                // critic: 32 parts x 16 MAC
        int part = tid - 128;
        float acc = 0.f;
        const float* z0 = z1 + part*16;
        #pragma unroll 8
        for (int h = 0; h < 16; ++h) acc += z0[h]*cw[part*16 + h];
        pc[part] = acc;
    } else if (tid < 288) {                // upsilon: 4 e x 32 parts x 10 MAC
        int r = tid - 160;
        int e = r >> 5, part = r & 31;
        float acc = 0.f;
        #pragma unroll
        for (int k = 0; k < 10; ++k) acc += zin[part*10 + k]*uw[(part*10 + k)*NE + e];
        plu[e][part] = acc;
    } else if (tid < 352) {                // dgate: 2 g x 32 parts x 10 MAC
        int r = tid - 288;
        int g = r >> 5, part = r & 31;
        float acc = 0.f;
        #pragma unroll
        for (int k = 0; k < 10; ++k) acc += zin[part*10 + k]*dw[(part*10 + k)*2 + g];
        pld[g][part] = acc;
    }
    __syncthreads();

    // stage B: final reductions
    if (tid < A_) {
        float acc = ab[tid];
        #pragma unroll
        for (int k = 0; k < 8; ++k) acc += pla[tid][k];
        la[tid] = acc;
    } else if (tid < A_ + NE) {
        int e = tid - A_;
        float acc = ub[e];
        #pragma unroll
        for (int k = 0; k < 32; ++k) acc += plu[e][k];
        lu[e] = acc;
    } else if (tid < A_ + NE + 2) {
        int g = tid - A_ - NE;
        float acc = db[g];
        #pragma unroll
        for (int k = 0; k < 32; ++k) acc += pld[g][k];
        ld2[g] = acc;
    } else if (tid == 24) {
        float acc = cb[0];
        #pragma unroll
        for (int k = 0; k < 32; ++k) acc += pc[k];
        sc[0] = acc;
    }
    __syncthreads();

    // stage C: softmaxes + argmaxes
    if (tid == 0) {
        float mx = la[0];
        #pragma unroll
        for (int k2 = 1; k2 < A_; ++k2) mx = fmaxf(mx, la[k2]);
        float pr[A_]; float sum = 0.f;
        #pragma unroll
        for (int k2 = 0; k2 < A_; ++k2) { pr[k2] = expf(la[k2]-mx); sum += pr[k2]; }
        const float* am = amask + ((size_t)t*N_ + n)*A_;
        float best = -1.f; int bi2 = 0;
        #pragma unroll
        for (int k2 = 0; k2 < A_; ++k2) {
            float v = pr[k2]/sum * am[k2];
            out[ob + 1 + k2] = v;
            if (v > best) { best = v; bi2 = k2; }
        }
        out[ob + 0] = (float)bi2;
    } else if (tid == 1) {
        float mx = fmaxf(fmaxf(lu[0], lu[1]), fmaxf(lu[2], lu[3]));
        float ev[NE]; float s0 = 0.f;
        #pragma unroll
        for (int e = 0; e < NE; ++e) { ev[e] = expf(lu[e]-mx); s0 += ev[e]; }
        #pragma unroll
        for (int e = 0; e < NE; ++e) uvals[e] = ev[e]/s0;
    } else if (tid == 2) {
        float mx = fmaxf(ld2[0], ld2[1]);
        float e0 = expf(ld2[0]-mx), e1 = expf(ld2[1]-mx);
        float s0 = e0 + e1;
        out[ob + 660] = e0/s0;
        out[ob + 661] = e1/s0;
        int dg = (ld2[1] > ld2[0]) ? 1 : 0;
        si[2] = dg;
        out[ob + 662] = (float)dg;
    }
    __syncthreads();
    if (tid < 128) {
        const float* Pp = Pall + ((size_t)(n*NL + si[0])*128 + tid)*NE;
        float v = Pp[0]*uvals[0] + Pp[1]*uvals[1] + Pp[2]*uvals[2] + Pp[3]*uvals[3];
        dp[tid] = v;
        out[ob + 18 + tid] = v;
    }
    __syncthreads();
    if (tid == 0) {
        int dsel;
        if (si[2] == 1) {
            float best = dp[0]; dsel = 0;
            for (int j2 = 1; j2 < 128; ++j2) if (dp[j2] > best) { best = dp[j2]; dsel = j2; }
        } else dsel = 64;
        int p = si[0];
        int pn = p + dsel - 64;
        pn = pn < 0 ? 0 : (pn > 63 ? 63 : pn);
        si[3] = pn;
        p_cur[n] = pn;
        out[ob + 17]  = (float)dsel;
        out[ob + 658] = (float)pn;
        out[ob + 659] = sc[0];
    }
    __syncthreads();
    if (tid < E_) {
        ((float*)mp_buf)[n*E_ + tid] = M[(n*NL + si[3])*E_ + tid];
    }
}

extern "C" void kernel_launch(void* const* d_in, const int* in_sizes, int n_in,
                              void* d_out, int out_size, void* d_ws, size_t ws_size,
                              hipStream_t stream) {
    (void)in_sizes; (void)n_in; (void)out_size; (void)ws_size;
    const int*   lines    = (const int*)  d_in[0];
    const float* obs      = (const float*)d_in[1];
    const float* invent   = (const float*)d_in[2];
    const int*   pa       = (const int*)  d_in[3];
    const float* amask    = (const float*)d_in[4];
    const int*   p0       = (const int*)  d_in[5];
    const float* emb_task = (const float*)d_in[6];
    const float* emb_low  = (const float*)d_in[7];
    const float* wi_f     = (const float*)d_in[8];
    const float* wh_f     = (const float*)d_in[9];
    const float* bi_f     = (const float*)d_in[10];
    const float* bh_f     = (const float*)d_in[11];
    const float* wi_b     = (const float*)d_in[12];
    const float* wh_b     = (const float*)d_in[13];
    const float* bi_b     = (const float*)d_in[14];
    const float* bh_b     = (const float*)d_in[15];
    const float* beta_w   = (const float*)d_in[16];
    const float* beta_b   = (const float*)d_in[17];
    const float* kernel_w = (const float*)d_in[18];
    const float* kernel_b = (const float*)d_in[19];
    const float* conv_b   = (const float*)d_in[20];
    const float* inv_w    = (const float*)d_in[21];
    const float* inv_b    = (const float*)d_in[22];
    const float* zw       = (const float*)d_in[23];
    const float* zb       = (const float*)d_in[24];
    const float* aw       = (const float*)d_in[25];
    const float* ab       = (const float*)d_in[26];
    const float* uw       = (const float*)d_in[27];
    const float* ub       = (const float*)d_in[28];
    const float* dw       = (const float*)d_in[29];
    const float* db       = (const float*)d_in[30];
    const float* cw       = (const float*)d_in[31];
    const float* cb       = (const float*)d_in[32];
    float* out = (float*)d_out;

    float* ws = (float*)d_ws;
    size_t off = 0;
    float* M        = ws + off; off += (size_t)N_*NL*E_;
    float* wiT4     = ws + off; off += 2*32*384*4;
    float* whT4     = ws + off; off += 2*32*384*4;
    float* giM      = ws + off; off += (size_t)2*N_*NL*G3;
    float* Ball     = ws + off; off += (size_t)N_*NL*128*NE;
    float* Pall     = ws + off; off += (size_t)N_*NL*128*NE;
    float* inv_all  = ws + off; off += (size_t)T_*N_*RH;
    float* pa_all   = ws + off; off += (size_t)T_*N_*LE;
    float* kern_buf = ws + off; off += (size_t)N_*KCOLS;
    float* mp_buf   = ws + off; off += (size_t)N_*E_;
    int*   p_cur    = (int*)(ws + off); off += 64;

    k_prep_M<<<N_*NL, 128, 0, stream>>>(lines, emb_task, M);
    k_prep_T4<<<768, 128, 0, stream>>>(wi_f, wi_b, wh_f, wh_b, wiT4, whT4);
    k_prep_misc<<<N_, 128, 0, stream>>>(p0, M, p_cur, mp_buf);
    k_prep_invpa<<<T_*N_, 64, 0, stream>>>(invent, inv_w, inv_b, pa, emb_low, inv_all, pa_all);
    k_giM<<<dim3(8, N_, 2), 384, 0, stream>>>(M, wiT4, bi_f, bi_b, giM);
    k_gru<<<dim3(4, N_, 2), 256, 0, stream>>>(giM, whT4, bh_f, bh_b, beta_w, beta_b, Ball);
    k_P<<<N_*NL, 64, 0, stream>>>(Ball, Pall);

    for (int t = 0; t < T_; ++t) {
        k_kern<<<KCOLS/32, 256, 0, stream>>>(mp_buf, kernel_w, kernel_b, kern_buf);
        k_step<<<N_, 512, 0, stream>>>(obs, kern_buf, conv_b,
                                       mp_buf, inv_all, pa_all, amask, Pall, M,
                                       zw, zb, aw, ab, uw, ub, dw, db, cw, cb,
                                       p_cur, out, t);
    }
}